// Round 8
// baseline (353.313 us; speedup 1.0000x reference)
//
#include <hip/hip_runtime.h>

#define NN 50000
#define NE 800000
#define F 128
#define NREL 4
#define RN (NREL * NN)          // number of segments
#define NB 196                  // scan blocks: ceil(RN / 1024)
#define BN_EPS 1e-5f
#define TILE 128                // rows per block tile
#define NT1 391                 // ceil(NN / TILE)
#define LDW 136                 // padded LDS row stride in bf16 elems

typedef __attribute__((ext_vector_type(8))) short short8;
typedef __attribute__((ext_vector_type(4))) float floatx4;

__device__ __forceinline__ ushort f2bf(float f) {
    union { float f; unsigned u; } v; v.f = f;
    unsigned r = v.u + 0x7fffu + ((v.u >> 16) & 1u);
    return (ushort)(r >> 16);
}
__device__ __forceinline__ float bf2f(ushort h) {
    union { unsigned u; float f; } v; v.u = ((unsigned)h) << 16;
    return v.f;
}
__device__ __forceinline__ float ubf(unsigned bits) {
    union { unsigned u; float f; } v; v.u = bits; return v.f;
}
__device__ __forceinline__ unsigned pk2(float a, float b) {
    return (unsigned)f2bf(a) | ((unsigned)f2bf(b) << 16);
}
__device__ __forceinline__ void acc_u4(float* acc, uint4 v) {
    acc[0] += ubf(v.x << 16); acc[1] += ubf(v.x & 0xffff0000u);
    acc[2] += ubf(v.y << 16); acc[3] += ubf(v.y & 0xffff0000u);
    acc[4] += ubf(v.z << 16); acc[5] += ubf(v.z & 0xffff0000u);
    acc[6] += ubf(v.w << 16); acc[7] += ubf(v.w & 0xffff0000u);
}

// ---------------- xb = bf16(x) ----------------
__global__ __launch_bounds__(256) void xb_kernel(
    const float* __restrict__ x, ushort* __restrict__ xb)
{
    int i = blockIdx.x * 256 + threadIdx.x;   // 4 floats/thread; NN*F/4 threads exactly
    float4 v = *(const float4*)(x + (size_t)i * 4);
    uint2 u;
    u.x = pk2(v.x, v.y);
    u.y = pk2(v.z, v.w);
    *(uint2*)(xb + (size_t)i * 4) = u;
}

// ---------------- histogram ----------------
__global__ __launch_bounds__(256) void hist_kernel(
    const int* __restrict__ ei, const int* __restrict__ et, int* __restrict__ counts)
{
    int e = blockIdx.x * 256 + threadIdx.x;
    if (e >= NE) return;
    atomicAdd(&counts[et[e] * NN + ei[NE + e]], 1);
}

// ---------------- scan stage 1 ----------------
__global__ __launch_bounds__(256) void scan1_kernel(
    const int* __restrict__ counts, int* __restrict__ rowptr, int* __restrict__ bsum)
{
    __shared__ int wsum[4];
    const int tid = threadIdx.x;
    const int base = blockIdx.x * 1024 + tid * 4;
    int c[4];
    #pragma unroll
    for (int j = 0; j < 4; j++) c[j] = (base + j < RN) ? counts[base + j] : 0;
    int tsum = c[0] + c[1] + c[2] + c[3];
    const int lane = tid & 63, wv = tid >> 6;
    int s = tsum;
    #pragma unroll
    for (int d = 1; d < 64; d <<= 1) { int t = __shfl_up(s, d); if (lane >= d) s += t; }
    if (lane == 63) wsum[wv] = s;
    __syncthreads();
    int wave_off = 0;
    #pragma unroll
    for (int w = 0; w < 4; w++) if (w < wv) wave_off += wsum[w];
    int run = wave_off + s - tsum;
    #pragma unroll
    for (int j = 0; j < 4; j++) {
        if (base + j < RN) rowptr[base + j] = run;
        run += c[j];
    }
    if (tid == 0) bsum[blockIdx.x] = wsum[0] + wsum[1] + wsum[2] + wsum[3];
}

// ---------------- scan stage 2 ----------------
__global__ __launch_bounds__(256) void scan2_kernel(
    const int* __restrict__ bsum, int* __restrict__ boff, int* __restrict__ rowptr)
{
    __shared__ int wsum[4];
    const int tid = threadIdx.x;
    int v = (tid < NB) ? bsum[tid] : 0;
    const int lane = tid & 63, wv = tid >> 6;
    int s = v;
    #pragma unroll
    for (int d = 1; d < 64; d <<= 1) { int t = __shfl_up(s, d); if (lane >= d) s += t; }
    if (lane == 63) wsum[wv] = s;
    __syncthreads();
    int wave_off = 0;
    #pragma unroll
    for (int w = 0; w < 4; w++) if (w < wv) wave_off += wsum[w];
    if (tid < NB) boff[tid] = wave_off + s - v;
    if (tid == 0) rowptr[RN] = wsum[0] + wsum[1] + wsum[2] + wsum[3];
}

// ---------------- scan stage 3 ----------------
__global__ __launch_bounds__(256) void scan3_kernel(
    int* __restrict__ rowptr, const int* __restrict__ boff, int* __restrict__ cursor)
{
    const int base = blockIdx.x * 1024 + threadIdx.x * 4;
    const int off = boff[blockIdx.x];
    #pragma unroll
    for (int j = 0; j < 4; j++) {
        int idx = base + j;
        if (idx < RN) { int v = rowptr[idx] + off; rowptr[idx] = v; cursor[idx] = v; }
    }
}

// ---------------- reorder ----------------
__global__ __launch_bounds__(256) void reorder_kernel(
    const int* __restrict__ ei, const int* __restrict__ et,
    int* __restrict__ cursor, int* __restrict__ sorted_src)
{
    int e = blockIdx.x * 256 + threadIdx.x;
    if (e >= NE) return;
    int key = et[e] * NN + ei[NE + e];
    int pos = atomicAdd(&cursor[key], 1);
    sorted_src[pos] = ei[e];
}

// ------- gather: hbuf[row] = bf16(xb[n] + sum_{e in seg(row)} xb[src_e]) -------
__global__ __launch_bounds__(256) void gather_kernel(
    const ushort* __restrict__ xb, const int* __restrict__ rowptr,
    const int* __restrict__ sorted_src, ushort* __restrict__ hbuf)
{
    const int t = blockIdx.x * 256 + threadIdx.x;
    const int row = t >> 4;               // segment id in [0, RN)
    const int lane = t & 15;              // 16 lanes x 8 bf16 = 128 feats
    const int n = row % NN;               // dst node

    const uint4* xv = (const uint4*)xb;   // row stride = 16 uint4
    float acc[8];
    {
        uint4 v = xv[n * 16 + lane];
        acc[0] = ubf(v.x << 16); acc[1] = ubf(v.x & 0xffff0000u);
        acc[2] = ubf(v.y << 16); acc[3] = ubf(v.y & 0xffff0000u);
        acc[4] = ubf(v.z << 16); acc[5] = ubf(v.z & 0xffff0000u);
        acc[6] = ubf(v.w << 16); acc[7] = ubf(v.w & 0xffff0000u);
    }
    int e = rowptr[row];
    const int e1 = rowptr[row + 1];
    for (; e + 4 <= e1; e += 4) {
        int s0 = sorted_src[e], s1 = sorted_src[e + 1];
        int s2 = sorted_src[e + 2], s3 = sorted_src[e + 3];
        uint4 a = xv[s0 * 16 + lane];
        uint4 b = xv[s1 * 16 + lane];
        uint4 c = xv[s2 * 16 + lane];
        uint4 d = xv[s3 * 16 + lane];
        acc_u4(acc, a); acc_u4(acc, b); acc_u4(acc, c); acc_u4(acc, d);
    }
    for (; e < e1; ++e) {
        int s0 = sorted_src[e];
        acc_u4(acc, xv[s0 * 16 + lane]);
    }
    uint4 o;
    o.x = pk2(acc[0], acc[1]);
    o.y = pk2(acc[2], acc[3]);
    o.z = pk2(acc[4], acc[5]);
    o.w = pk2(acc[6], acc[7]);
    *(uint4*)(hbuf + (size_t)row * F + lane * 8) = o;
}

// ---------------- prep: weights -> bf16 transposed Wt_g[mat][n][k] ----------------
__global__ __launch_bounds__(256) void prep_kernel(
    const float* __restrict__ W1, const float* __restrict__ W2,
    const float* __restrict__ Wself, ushort* __restrict__ Wt_g)
{
    __shared__ ushort Lt[F * F];
    int m = blockIdx.x;
    const float* src = (m < 4) ? (W1 + (size_t)m * F * F)
                     : (m < 8) ? (W2 + (size_t)(m - 4) * F * F)
                               : Wself;
    int tid = threadIdx.x;
    #pragma unroll
    for (int p = 0; p < 16; p++) {
        int i4 = tid + p * 256;
        int k = i4 >> 5;
        int n4 = (i4 & 31) * 4;
        float4 v = *(const float4*)(src + (size_t)k * F + n4);
        Lt[(n4 + 0) * F + k] = f2bf(v.x);
        Lt[(n4 + 1) * F + k] = f2bf(v.y);
        Lt[(n4 + 2) * F + k] = f2bf(v.z);
        Lt[(n4 + 3) * F + k] = f2bf(v.w);
    }
    __syncthreads();
    #pragma unroll
    for (int p = 0; p < 8; p++) {
        int c = tid + p * 256;
        *(uint4*)(Wt_g + (size_t)m * F * F + c * 8) = *(const uint4*)&Lt[c * 8];
    }
}

// ------ GEMM1: h1 = bf16(hbuf @ W1[r] + b1[r]) in-place; per-block BN partials ------
// LDS: Wt only (34.8 KB); A direct global->VGPR; Wt region reused for C transpose.
__global__ __launch_bounds__(256, 4) void gemm1_kernel(
    ushort* __restrict__ hbuf, const ushort* __restrict__ Wt_g,
    const float* __restrict__ b1, float* __restrict__ partials)
{
    __shared__ __attribute__((aligned(16))) ushort Wt[F * LDW];   // 34.8 KB, reused as At
    __shared__ float csum[F], csq[F];

    const int tid = threadIdx.x;
    const int r = blockIdx.y;
    const int n0 = blockIdx.x * TILE;
    const int lane = tid & 63, w = tid >> 6;
    const int m = lane & 15, quad = lane >> 4;

    if (tid < F) { csum[tid] = 0.f; csq[tid] = 0.f; }

    // stage Wt (128 rows x 16 chunks of 8 ushorts)
    {
        const ushort* wg = Wt_g + (size_t)r * F * F;
        #pragma unroll
        for (int p = 0; p < 8; p++) {
            int c = tid + p * 256;
            int n = c >> 4, off = (c & 15) * 8;
            *(uint4*)&Wt[n * LDW + off] = *(const uint4*)(wg + c * 8);
        }
    }
    __syncthreads();

    // A direct from global: rows w*32 + {0..15, 16..31}
    const ushort* Ap0 = hbuf + ((size_t)r * NN + n0 + w * 32 + m) * F + quad * 8;
    const ushort* Ap1 = Ap0 + 16 * F;
    const ushort* Bp  = &Wt[m * LDW + quad * 8];

    floatx4 acc[2][8];
    #pragma unroll
    for (int rg = 0; rg < 2; rg++)
        #pragma unroll
        for (int g = 0; g < 8; g++) acc[rg][g] = (floatx4)0.f;

    #pragma unroll
    for (int kk = 0; kk < 4; kk++) {
        short8 a0 = *(const short8*)(Ap0 + kk * 32);
        short8 a1 = *(const short8*)(Ap1 + kk * 32);
        #pragma unroll
        for (int g = 0; g < 8; g++) {
            short8 b = *(const short8*)(Bp + g * 16 * LDW + kk * 32);
            acc[0][g] = __builtin_amdgcn_mfma_f32_16x16x32_bf16(a0, b, acc[0][g], 0, 0, 0);
            acc[1][g] = __builtin_amdgcn_mfma_f32_16x16x32_bf16(a1, b, acc[1][g], 0, 0, 0);
        }
    }
    __syncthreads();   // all waves done reading Wt -> reuse as At

    ushort* At = Wt;
    #pragma unroll
    for (int rg = 0; rg < 2; rg++) {
        const int rb = w * 32 + rg * 16;
        #pragma unroll
        for (int g = 0; g < 8; g++) {
            int c = g * 16 + m;
            float bv = b1[r * F + c];
            float ls = 0.f, lq = 0.f;
            #pragma unroll
            for (int i = 0; i < 4; i++) {
                int lrow = rb + quad * 4 + i;
                float v = acc[rg][g][i] + bv;
                At[lrow * LDW + c] = f2bf(v);
                if (n0 + lrow < NN) { ls += v; lq += v * v; }
            }
            ls += __shfl_xor(ls, 16); ls += __shfl_xor(ls, 32);
            lq += __shfl_xor(lq, 16); lq += __shfl_xor(lq, 32);
            if (quad == 0) { atomicAdd(&csum[c], ls); atomicAdd(&csq[c], lq); }
        }
    }
    __syncthreads();

    // coalesced in-place write-back + one coalesced partial row per block
    #pragma unroll
    for (int p = 0; p < 8; p++) {
        int cc = tid + p * 256;
        int row = cc >> 4, off = (cc & 15) * 8;
        if (n0 + row < NN)
            *(uint4*)(hbuf + ((size_t)r * NN + n0 + row) * F + off) =
                *(const uint4*)&At[row * LDW + off];
    }
    partials[((size_t)r * NT1 + blockIdx.x) * 256 + tid] =
        (tid < F) ? csum[tid] : csq[tid - F];
}

// ---------------- bncoef: parallel reduce partials -> sa/sb; btot ----------------
// 64 blocks x 256 threads: 32 lanes per (rel,col) pair
__global__ __launch_bounds__(256) void bncoef_kernel(
    const float* __restrict__ partials,
    const float* __restrict__ gamma, const float* __restrict__ beta,
    const float* __restrict__ b2, const float* __restrict__ bself,
    float* __restrict__ sa, float* __restrict__ sb, float* __restrict__ btot)
{
    const int tid = threadIdx.x;
    const int pair = blockIdx.x * 8 + (tid >> 5);     // 0..511
    const int l32 = tid & 31;
    const int rel = pair >> 7, col = pair & 127;
    const float* p = partials + (size_t)rel * NT1 * 256;
    float s = 0.f, q = 0.f;
    for (int b = l32; b < NT1; b += 32) {
        s += p[b * 256 + col];
        q += p[b * 256 + 128 + col];
    }
    #pragma unroll
    for (int d = 1; d < 32; d <<= 1) {
        s += __shfl_xor(s, d, 32);
        q += __shfl_xor(q, d, 32);
    }
    if (l32 == 0) {
        float mean = s * (1.0f / NN);
        float var = q * (1.0f / NN) - mean * mean;
        float g = gamma[pair] * rsqrtf(var + BN_EPS);
        sa[pair] = g;
        sb[pair] = beta[pair] - mean * g;
    }
    if (blockIdx.x == 0 && tid < F)
        btot[tid] = bself[tid] + b2[tid] + b2[F + tid] + b2[2 * F + tid] + b2[3 * F + tid];
}

// ------- GEMM2: out = xb@Wself + sum_r relu(bn(h1_r))@W2[r] + btot -------
// LDS: Wt only; A direct global->VGPR with in-register BN+ReLU; direct C-layout stores.
__global__ __launch_bounds__(256, 4) void gemm2_kernel(
    const ushort* __restrict__ xb, const ushort* __restrict__ h1,
    const ushort* __restrict__ Wt_g,
    const float* __restrict__ sa, const float* __restrict__ sb,
    const float* __restrict__ btot, float* __restrict__ out)
{
    __shared__ __attribute__((aligned(16))) ushort Wt[F * LDW];   // 34.8 KB
    __shared__ float sAl[NREL * F], sBl[NREL * F];

    const int tid = threadIdx.x;
    const int n0 = blockIdx.x * TILE;
    const int lane = tid & 63, w = tid >> 6;
    const int m = lane & 15, quad = lane >> 4;
    const int koff = quad * 8;

    #pragma unroll
    for (int p = 0; p < 2; p++) {
        int idx = tid + p * 256;
        sAl[idx] = sa[idx];
        sBl[idx] = sb[idx];
    }

    floatx4 acc[2][8];
    #pragma unroll
    for (int rg = 0; rg < 2; rg++)
        #pragma unroll
        for (int g = 0; g < 8; g++) acc[rg][g] = (floatx4)0.f;

    for (int rel = 0; rel < 5; rel++) {
        __syncthreads();   // prior Wt readers done (and sAl/sBl ready on first iter)
        {
            int mat = (rel < 4) ? (NREL + rel) : 8;
            const ushort* wg = Wt_g + (size_t)mat * F * F;
            #pragma unroll
            for (int p = 0; p < 8; p++) {
                int c = tid + p * 256;
                int n = c >> 4, off = (c & 15) * 8;
                *(uint4*)&Wt[n * LDW + off] = *(const uint4*)(wg + c * 8);
            }
        }
        __syncthreads();
        const ushort* Bp = &Wt[m * LDW + koff];
        if (rel < 4) {
            const ushort* hp0 = h1 + ((size_t)rel * NN + n0 + w * 32 + m) * F + koff;
            const ushort* hp1 = hp0 + 16 * F;
            #pragma unroll
            for (int kk = 0; kk < 4; kk++) {
                uint4 rv0 = *(const uint4*)(hp0 + kk * 32);
                uint4 rv1 = *(const uint4*)(hp1 + kk * 32);
                float4 ca0 = *(const float4*)(&sAl[rel * F + koff + kk * 32]);
                float4 ca1 = *(const float4*)(&sAl[rel * F + koff + kk * 32 + 4]);
                float4 cb0 = *(const float4*)(&sBl[rel * F + koff + kk * 32]);
                float4 cb1 = *(const float4*)(&sBl[rel * F + koff + kk * 32 + 4]);
                union { uint4 u; short8 s; } a0, a1;
                a0.u.x = pk2(fmaxf(fmaf(ubf(rv0.x << 16),         ca0.x, cb0.x), 0.f),
                             fmaxf(fmaf(ubf(rv0.x & 0xffff0000u), ca0.y, cb0.y), 0.f));
                a0.u.y = pk2(fmaxf(fmaf(ubf(rv0.y << 16),         ca0.z, cb0.z), 0.f),
                             fmaxf(fmaf(ubf(rv0.y & 0xffff0000u), ca0.w, cb0.w), 0.f));
                a0.u.z = pk2(fmaxf(fmaf(ubf(rv0.z << 16),         ca1.x, cb1.x), 0.f),
                             fmaxf(fmaf(ubf(rv0.z & 0xffff0000u), ca1.y, cb1.y), 0.f));
                a0.u.w = pk2(fmaxf(fmaf(ubf(rv0.w << 16),         ca1.z, cb1.z), 0.f),
                             fmaxf(fmaf(ubf(rv0.w & 0xffff0000u), ca1.w, cb1.w), 0.f));
                a1.u.x = pk2(fmaxf(fmaf(ubf(rv1.x << 16),         ca0.x, cb0.x), 0.f),
                             fmaxf(fmaf(ubf(rv1.x & 0xffff0000u), ca0.y, cb0.y), 0.f));
                a1.u.y = pk2(fmaxf(fmaf(ubf(rv1.y << 16),         ca0.z, cb0.z), 0.f),
                             fmaxf(fmaf(ubf(rv1.y & 0xffff0000u), ca0.w, cb0.w), 0.f));
                a1.u.z = pk2(fmaxf(fmaf(ubf(rv1.z << 16),         ca1.x, cb1.x), 0.f),
                             fmaxf(fmaf(ubf(rv1.z & 0xffff0000u), ca1.y, cb1.y), 0.f));
                a1.u.w = pk2(fmaxf(fmaf(ubf(rv1.w << 16),         ca1.z, cb1.z), 0.f),
                             fmaxf(fmaf(ubf(rv1.w & 0xffff0000u), ca1.w, cb1.w), 0.f));
                #pragma unroll
                for (int g = 0; g < 8; g++) {
                    short8 b = *(const short8*)(Bp + g * 16 * LDW + kk * 32);
                    acc[0][g] = __builtin_amdgcn_mfma_f32_16x16x32_bf16(a0.s, b, acc[0][g], 0, 0, 0);
                    acc[1][g] = __builtin_amdgcn_mfma_f32_16x16x32_bf16(a1.s, b, acc[1][g], 0, 0, 0);
                }
            }
        } else {
            const ushort* xp0 = xb + (size_t)(n0 + w * 32 + m) * F + koff;
            const ushort* xp1 = xp0 + 16 * F;
            #pragma unroll
            for (int kk = 0; kk < 4; kk++) {
                short8 a0 = *(const short8*)(xp0 + kk * 32);
                short8 a1 = *(const short8*)(xp1 + kk * 32);
                #pragma unroll
                for (int g = 0; g < 8; g++) {
                    short8 b = *(const short8*)(Bp + g * 16 * LDW + kk * 32);
                    acc[0][g] = __builtin_amdgcn_mfma_f32_16x16x32_bf16(a0, b, acc[0][g], 0, 0, 0);
                    acc[1][g] = __builtin_amdgcn_mfma_f32_16x16x32_bf16(a1, b, acc[1][g], 0, 0, 0);
                }
            }
        }
    }

    // epilogue: direct C-layout f32 stores (quad rows x 64B contiguous per (g,i))
    #pragma unroll
    for (int rg = 0; rg < 2; rg++) {
        const int rb = w * 32 + rg * 16;
        #pragma unroll
        for (int g = 0; g < 8; g++) {
            int c = g * 16 + m;
            float bv = btot[c];
            #pragma unroll
            for (int i = 0; i < 4; i++) {
                int n = n0 + rb + quad * 4 + i;
                if (n < NN) out[(size_t)n * F + c] = acc[rg][g][i] + bv;
            }
        }
    }
}

extern "C" void kernel_launch(void* const* d_in, const int* in_sizes, int n_in,
                              void* d_out, int out_size, void* d_ws, size_t ws_size,
                              hipStream_t stream) {
    const float* x     = (const float*)d_in[0];
    const int*   ei    = (const int*)d_in[1];
    const int*   et    = (const int*)d_in[2];
    const float* Wself = (const float*)d_in[3];
    const float* bself = (const float*)d_in[4];
    const float* W1    = (const float*)d_in[5];
    const float* b1    = (const float*)d_in[6];
    const float* gamma = (const float*)d_in[7];
    const float* beta  = (const float*)d_in[8];
    const float* W2    = (const float*)d_in[9];
    const float* b2    = (const float*)d_in[10];
    float* out = (float*)d_out;

    // workspace layout
    ushort* hbuf = (ushort*)d_ws;                       // [4, NN, 128] bf16: h_in -> h1 in-place
    ushort* xb   = hbuf + (size_t)RN * F;               // [NN, 128] bf16
    ushort* Wt_g = xb + (size_t)NN * F;                 // [9, 128, 128] bf16
    float*  partials = (float*)(Wt_g + 9 * F * F);      // [4, NT1, 256]
    float*  sa    = partials + (size_t)NREL * NT1 * 256;// [4, 128]
    float*  sb    = sa + NREL * F;                      // [4, 128]
    float*  btot  = sb + NREL * F;                      // [128]
    int* counts     = (int*)(btot + F);                 // [RN]
    int* rowptr     = counts + RN;                      // [RN+1]
    int* cursor     = rowptr + RN + 1;                  // [RN]
    int* sorted_src = cursor + RN;                      // [NE]
    int* bsum       = sorted_src + NE;                  // [256]
    int* boff       = bsum + 256;                       // [256]

    hipMemsetAsync(counts, 0, (size_t)RN * sizeof(int), stream);

    prep_kernel<<<9, 256, 0, stream>>>(W1, W2, Wself, Wt_g);
    xb_kernel<<<NN * F / 1024, 256, 0, stream>>>(x, xb);
    hist_kernel<<<(NE + 255) / 256, 256, 0, stream>>>(ei, et, counts);
    scan1_kernel<<<NB, 256, 0, stream>>>(counts, rowptr, bsum);
    scan2_kernel<<<1, 256, 0, stream>>>(bsum, boff, rowptr);
    scan3_kernel<<<NB, 256, 0, stream>>>(rowptr, boff, cursor);
    reorder_kernel<<<(NE + 255) / 256, 256, 0, stream>>>(ei, et, cursor, sorted_src);
    gather_kernel<<<RN * 16 / 256, 256, 0, stream>>>(xb, rowptr, sorted_src, hbuf);
    {
        dim3 grid(NT1, NREL);
        gemm1_kernel<<<grid, 256, 0, stream>>>(hbuf, Wt_g, b1, partials);
    }
    bncoef_kernel<<<64, 256, 0, stream>>>(partials, gamma, beta, b2, bself, sa, sb, btot);
    gemm2_kernel<<<NT1, 256, 0, stream>>>(xb, hbuf, Wt_g, sa, sb, btot, out);
}

// Round 9
// 344.867 us; speedup vs baseline: 1.0245x; 1.0245x over previous
//
#include <hip/hip_runtime.h>

#define NN 50000
#define NE 800000
#define F 128
#define NREL 4
#define RN (NREL * NN)          // number of segments
#define NB 196                  // scan blocks: ceil(RN / 1024)
#define BN_EPS 1e-5f
#define TILE 128                // rows per block tile
#define NT1 391                 // ceil(NN / TILE)
#define LDW 136                 // padded LDS row stride in bf16 elems
#define CTS 132                 // padded f32 Ct row stride

typedef __attribute__((ext_vector_type(8))) short short8;
typedef __attribute__((ext_vector_type(4))) float floatx4;

__device__ __forceinline__ ushort f2bf(float f) {
    union { float f; unsigned u; } v; v.f = f;
    unsigned r = v.u + 0x7fffu + ((v.u >> 16) & 1u);
    return (ushort)(r >> 16);
}
__device__ __forceinline__ float bf2f(ushort h) {
    union { unsigned u; float f; } v; v.u = ((unsigned)h) << 16;
    return v.f;
}
__device__ __forceinline__ float ubf(unsigned bits) {
    union { unsigned u; float f; } v; v.u = bits; return v.f;
}
__device__ __forceinline__ unsigned pk2(float a, float b) {
    return (unsigned)f2bf(a) | ((unsigned)f2bf(b) << 16);
}
__device__ __forceinline__ void acc_u4(float* acc, uint4 v) {
    acc[0] += ubf(v.x << 16); acc[1] += ubf(v.x & 0xffff0000u);
    acc[2] += ubf(v.y << 16); acc[3] += ubf(v.y & 0xffff0000u);
    acc[4] += ubf(v.z << 16); acc[5] += ubf(v.z & 0xffff0000u);
    acc[6] += ubf(v.w << 16); acc[7] += ubf(v.w & 0xffff0000u);
}

// ---------------- xb = bf16(x) ----------------
__global__ __launch_bounds__(256) void xb_kernel(
    const float* __restrict__ x, ushort* __restrict__ xb)
{
    int i = blockIdx.x * 256 + threadIdx.x;   // 4 floats/thread; NN*F/4 threads exactly
    float4 v = *(const float4*)(x + (size_t)i * 4);
    uint2 u;
    u.x = pk2(v.x, v.y);
    u.y = pk2(v.z, v.w);
    *(uint2*)(xb + (size_t)i * 4) = u;
}

// ---------------- histogram ----------------
__global__ __launch_bounds__(256) void hist_kernel(
    const int* __restrict__ ei, const int* __restrict__ et, int* __restrict__ counts)
{
    int e = blockIdx.x * 256 + threadIdx.x;
    if (e >= NE) return;
    atomicAdd(&counts[et[e] * NN + ei[NE + e]], 1);
}

// ---------------- scan stage 1 ----------------
__global__ __launch_bounds__(256) void scan1_kernel(
    const int* __restrict__ counts, int* __restrict__ rowptr, int* __restrict__ bsum)
{
    __shared__ int wsum[4];
    const int tid = threadIdx.x;
    const int base = blockIdx.x * 1024 + tid * 4;
    int c[4];
    #pragma unroll
    for (int j = 0; j < 4; j++) c[j] = (base + j < RN) ? counts[base + j] : 0;
    int tsum = c[0] + c[1] + c[2] + c[3];
    const int lane = tid & 63, wv = tid >> 6;
    int s = tsum;
    #pragma unroll
    for (int d = 1; d < 64; d <<= 1) { int t = __shfl_up(s, d); if (lane >= d) s += t; }
    if (lane == 63) wsum[wv] = s;
    __syncthreads();
    int wave_off = 0;
    #pragma unroll
    for (int w = 0; w < 4; w++) if (w < wv) wave_off += wsum[w];
    int run = wave_off + s - tsum;
    #pragma unroll
    for (int j = 0; j < 4; j++) {
        if (base + j < RN) rowptr[base + j] = run;
        run += c[j];
    }
    if (tid == 0) bsum[blockIdx.x] = wsum[0] + wsum[1] + wsum[2] + wsum[3];
}

// ---------------- scan stage 2 ----------------
__global__ __launch_bounds__(256) void scan2_kernel(
    const int* __restrict__ bsum, int* __restrict__ boff, int* __restrict__ rowptr)
{
    __shared__ int wsum[4];
    const int tid = threadIdx.x;
    int v = (tid < NB) ? bsum[tid] : 0;
    const int lane = tid & 63, wv = tid >> 6;
    int s = v;
    #pragma unroll
    for (int d = 1; d < 64; d <<= 1) { int t = __shfl_up(s, d); if (lane >= d) s += t; }
    if (lane == 63) wsum[wv] = s;
    __syncthreads();
    int wave_off = 0;
    #pragma unroll
    for (int w = 0; w < 4; w++) if (w < wv) wave_off += wsum[w];
    if (tid < NB) boff[tid] = wave_off + s - v;
    if (tid == 0) rowptr[RN] = wsum[0] + wsum[1] + wsum[2] + wsum[3];
}

// ---------------- scan stage 3 ----------------
__global__ __launch_bounds__(256) void scan3_kernel(
    int* __restrict__ rowptr, const int* __restrict__ boff, int* __restrict__ cursor)
{
    const int base = blockIdx.x * 1024 + threadIdx.x * 4;
    const int off = boff[blockIdx.x];
    #pragma unroll
    for (int j = 0; j < 4; j++) {
        int idx = base + j;
        if (idx < RN) { int v = rowptr[idx] + off; rowptr[idx] = v; cursor[idx] = v; }
    }
}

// ---------------- reorder ----------------
__global__ __launch_bounds__(256) void reorder_kernel(
    const int* __restrict__ ei, const int* __restrict__ et,
    int* __restrict__ cursor, int* __restrict__ sorted_src)
{
    int e = blockIdx.x * 256 + threadIdx.x;
    if (e >= NE) return;
    int key = et[e] * NN + ei[NE + e];
    int pos = atomicAdd(&cursor[key], 1);
    sorted_src[pos] = ei[e];
}

// ------- gather: hbuf[row] = bf16(xb[n] + sum_{e in seg(row)} xb[src_e]) -------
__global__ __launch_bounds__(256) void gather_kernel(
    const ushort* __restrict__ xb, const int* __restrict__ rowptr,
    const int* __restrict__ sorted_src, ushort* __restrict__ hbuf)
{
    const int t = blockIdx.x * 256 + threadIdx.x;
    const int row = t >> 4;               // segment id in [0, RN)
    const int lane = t & 15;              // 16 lanes x 8 bf16 = 128 feats
    const int n = row % NN;               // dst node

    const uint4* xv = (const uint4*)xb;   // row stride = 16 uint4
    float acc[8];
    {
        uint4 v = xv[n * 16 + lane];
        acc[0] = ubf(v.x << 16); acc[1] = ubf(v.x & 0xffff0000u);
        acc[2] = ubf(v.y << 16); acc[3] = ubf(v.y & 0xffff0000u);
        acc[4] = ubf(v.z << 16); acc[5] = ubf(v.z & 0xffff0000u);
        acc[6] = ubf(v.w << 16); acc[7] = ubf(v.w & 0xffff0000u);
    }
    int e = rowptr[row];
    const int e1 = rowptr[row + 1];
    for (; e + 4 <= e1; e += 4) {
        int s0 = sorted_src[e], s1 = sorted_src[e + 1];
        int s2 = sorted_src[e + 2], s3 = sorted_src[e + 3];
        uint4 a = xv[s0 * 16 + lane];
        uint4 b = xv[s1 * 16 + lane];
        uint4 c = xv[s2 * 16 + lane];
        uint4 d = xv[s3 * 16 + lane];
        acc_u4(acc, a); acc_u4(acc, b); acc_u4(acc, c); acc_u4(acc, d);
    }
    for (; e < e1; ++e) {
        int s0 = sorted_src[e];
        acc_u4(acc, xv[s0 * 16 + lane]);
    }
    uint4 o;
    o.x = pk2(acc[0], acc[1]);
    o.y = pk2(acc[2], acc[3]);
    o.z = pk2(acc[4], acc[5]);
    o.w = pk2(acc[6], acc[7]);
    *(uint4*)(hbuf + (size_t)row * F + lane * 8) = o;
}

// ---------------- prep: weights -> bf16 transposed Wt_g[mat][n][k] ----------------
__global__ __launch_bounds__(256) void prep_kernel(
    const float* __restrict__ W1, const float* __restrict__ W2,
    const float* __restrict__ Wself, ushort* __restrict__ Wt_g)
{
    __shared__ ushort Lt[F * F];
    int m = blockIdx.x;
    const float* src = (m < 4) ? (W1 + (size_t)m * F * F)
                     : (m < 8) ? (W2 + (size_t)(m - 4) * F * F)
                               : Wself;
    int tid = threadIdx.x;
    #pragma unroll
    for (int p = 0; p < 16; p++) {
        int i4 = tid + p * 256;
        int k = i4 >> 5;
        int n4 = (i4 & 31) * 4;
        float4 v = *(const float4*)(src + (size_t)k * F + n4);
        Lt[(n4 + 0) * F + k] = f2bf(v.x);
        Lt[(n4 + 1) * F + k] = f2bf(v.y);
        Lt[(n4 + 2) * F + k] = f2bf(v.z);
        Lt[(n4 + 3) * F + k] = f2bf(v.w);
    }
    __syncthreads();
    #pragma unroll
    for (int p = 0; p < 8; p++) {
        int c = tid + p * 256;
        *(uint4*)(Wt_g + (size_t)m * F * F + c * 8) = *(const uint4*)&Lt[c * 8];
    }
}

// ------ GEMM1: h1 = bf16(hbuf @ W1[r] + b1[r]) in-place; per-block BN partials ------
// LDS: Wt only (34.8 KB); A direct global->VGPR; Wt region reused for C transpose.
__global__ __launch_bounds__(256, 4) void gemm1_kernel(
    ushort* __restrict__ hbuf, const ushort* __restrict__ Wt_g,
    const float* __restrict__ b1, float* __restrict__ partials)
{
    __shared__ __attribute__((aligned(16))) ushort Wt[F * LDW];   // 34.8 KB, reused as At
    __shared__ float csum[F], csq[F];

    const int tid = threadIdx.x;
    const int r = blockIdx.y;
    const int n0 = blockIdx.x * TILE;
    const int lane = tid & 63, w = tid >> 6;
    const int m = lane & 15, quad = lane >> 4;

    if (tid < F) { csum[tid] = 0.f; csq[tid] = 0.f; }

    // stage Wt (128 rows x 16 chunks of 8 ushorts)
    {
        const ushort* wg = Wt_g + (size_t)r * F * F;
        #pragma unroll
        for (int p = 0; p < 8; p++) {
            int c = tid + p * 256;
            int n = c >> 4, off = (c & 15) * 8;
            *(uint4*)&Wt[n * LDW + off] = *(const uint4*)(wg + c * 8);
        }
    }
    __syncthreads();

    // A direct from global: rows w*32 + {0..15, 16..31}
    const ushort* Ap0 = hbuf + ((size_t)r * NN + n0 + w * 32 + m) * F + quad * 8;
    const ushort* Ap1 = Ap0 + 16 * F;
    const ushort* Bp  = &Wt[m * LDW + quad * 8];

    floatx4 acc[2][8];
    #pragma unroll
    for (int rg = 0; rg < 2; rg++)
        #pragma unroll
        for (int g = 0; g < 8; g++) acc[rg][g] = (floatx4)0.f;

    #pragma unroll
    for (int kk = 0; kk < 4; kk++) {
        short8 a0 = *(const short8*)(Ap0 + kk * 32);
        short8 a1 = *(const short8*)(Ap1 + kk * 32);
        #pragma unroll
        for (int g = 0; g < 8; g++) {
            short8 b = *(const short8*)(Bp + g * 16 * LDW + kk * 32);
            acc[0][g] = __builtin_amdgcn_mfma_f32_16x16x32_bf16(a0, b, acc[0][g], 0, 0, 0);
            acc[1][g] = __builtin_amdgcn_mfma_f32_16x16x32_bf16(a1, b, acc[1][g], 0, 0, 0);
        }
    }
    __syncthreads();   // all waves done reading Wt -> reuse as At

    ushort* At = Wt;
    #pragma unroll
    for (int rg = 0; rg < 2; rg++) {
        const int rb = w * 32 + rg * 16;
        #pragma unroll
        for (int g = 0; g < 8; g++) {
            int c = g * 16 + m;
            float bv = b1[r * F + c];
            float ls = 0.f, lq = 0.f;
            #pragma unroll
            for (int i = 0; i < 4; i++) {
                int lrow = rb + quad * 4 + i;
                float v = acc[rg][g][i] + bv;
                At[lrow * LDW + c] = f2bf(v);
                if (n0 + lrow < NN) { ls += v; lq += v * v; }
            }
            ls += __shfl_xor(ls, 16); ls += __shfl_xor(ls, 32);
            lq += __shfl_xor(lq, 16); lq += __shfl_xor(lq, 32);
            if (quad == 0) { atomicAdd(&csum[c], ls); atomicAdd(&csq[c], lq); }
        }
    }
    __syncthreads();

    // coalesced in-place write-back + one coalesced partial row per block
    #pragma unroll
    for (int p = 0; p < 8; p++) {
        int cc = tid + p * 256;
        int row = cc >> 4, off = (cc & 15) * 8;
        if (n0 + row < NN)
            *(uint4*)(hbuf + ((size_t)r * NN + n0 + row) * F + off) =
                *(const uint4*)&At[row * LDW + off];
    }
    partials[((size_t)r * NT1 + blockIdx.x) * 256 + tid] =
        (tid < F) ? csum[tid] : csq[tid - F];
}

// ---------------- bncoef: parallel reduce partials -> sa/sb; btot ----------------
__global__ __launch_bounds__(256) void bncoef_kernel(
    const float* __restrict__ partials,
    const float* __restrict__ gamma, const float* __restrict__ beta,
    const float* __restrict__ b2, const float* __restrict__ bself,
    float* __restrict__ sa, float* __restrict__ sb, float* __restrict__ btot)
{
    const int tid = threadIdx.x;
    const int pair = blockIdx.x * 8 + (tid >> 5);     // 0..511
    const int l32 = tid & 31;
    const int rel = pair >> 7, col = pair & 127;
    const float* p = partials + (size_t)rel * NT1 * 256;
    float s = 0.f, q = 0.f;
    for (int b = l32; b < NT1; b += 32) {
        s += p[b * 256 + col];
        q += p[b * 256 + 128 + col];
    }
    #pragma unroll
    for (int d = 1; d < 32; d <<= 1) {
        s += __shfl_xor(s, d, 32);
        q += __shfl_xor(q, d, 32);
    }
    if (l32 == 0) {
        float mean = s * (1.0f / NN);
        float var = q * (1.0f / NN) - mean * mean;
        float g = gamma[pair] * rsqrtf(var + BN_EPS);
        sa[pair] = g;
        sb[pair] = beta[pair] - mean * g;
    }
    if (blockIdx.x == 0 && tid < F)
        btot[tid] = bself[tid] + b2[tid] + b2[F + tid] + b2[2 * F + tid] + b2[3 * F + tid];
}

// ------- GEMM2: out = xb@Wself + sum_r relu(bn(h1_r))@W2[r] + btot -------
// LDS: Wt only (operands); two-pass f32 Ct transpose reusing Wt for coalesced stores.
__global__ __launch_bounds__(256, 4) void gemm2_kernel(
    const ushort* __restrict__ xb, const ushort* __restrict__ h1,
    const ushort* __restrict__ Wt_g,
    const float* __restrict__ sa, const float* __restrict__ sb,
    const float* __restrict__ btot, float* __restrict__ out)
{
    __shared__ __attribute__((aligned(16))) ushort Wt[F * LDW];   // 34.8 KB; Ct reuse
    __shared__ float sAl[NREL * F], sBl[NREL * F];

    const int tid = threadIdx.x;
    const int n0 = blockIdx.x * TILE;
    const int lane = tid & 63, w = tid >> 6;
    const int m = lane & 15, quad = lane >> 4;
    const int koff = quad * 8;

    #pragma unroll
    for (int p = 0; p < 2; p++) {
        int idx = tid + p * 256;
        sAl[idx] = sa[idx];
        sBl[idx] = sb[idx];
    }

    floatx4 acc[2][8];
    #pragma unroll
    for (int rg = 0; rg < 2; rg++)
        #pragma unroll
        for (int g = 0; g < 8; g++) acc[rg][g] = (floatx4)0.f;

    for (int rel = 0; rel < 5; rel++) {
        __syncthreads();   // prior Wt readers done (and sAl/sBl ready on first iter)
        {
            int mat = (rel < 4) ? (NREL + rel) : 8;
            const ushort* wg = Wt_g + (size_t)mat * F * F;
            #pragma unroll
            for (int p = 0; p < 8; p++) {
                int c = tid + p * 256;
                int n = c >> 4, off = (c & 15) * 8;
                *(uint4*)&Wt[n * LDW + off] = *(const uint4*)(wg + c * 8);
            }
        }
        __syncthreads();
        const ushort* Bp = &Wt[m * LDW + koff];
        if (rel < 4) {
            const ushort* hp0 = h1 + ((size_t)rel * NN + n0 + w * 32 + m) * F + koff;
            const ushort* hp1 = hp0 + 16 * F;
            #pragma unroll
            for (int kk = 0; kk < 4; kk++) {
                uint4 rv0 = *(const uint4*)(hp0 + kk * 32);
                uint4 rv1 = *(const uint4*)(hp1 + kk * 32);
                float4 ca0 = *(const float4*)(&sAl[rel * F + koff + kk * 32]);
                float4 ca1 = *(const float4*)(&sAl[rel * F + koff + kk * 32 + 4]);
                float4 cb0 = *(const float4*)(&sBl[rel * F + koff + kk * 32]);
                float4 cb1 = *(const float4*)(&sBl[rel * F + koff + kk * 32 + 4]);
                union { uint4 u; short8 s; } a0, a1;
                a0.u.x = pk2(fmaxf(fmaf(ubf(rv0.x << 16),         ca0.x, cb0.x), 0.f),
                             fmaxf(fmaf(ubf(rv0.x & 0xffff0000u), ca0.y, cb0.y), 0.f));
                a0.u.y = pk2(fmaxf(fmaf(ubf(rv0.y << 16),         ca0.z, cb0.z), 0.f),
                             fmaxf(fmaf(ubf(rv0.y & 0xffff0000u), ca0.w, cb0.w), 0.f));
                a0.u.z = pk2(fmaxf(fmaf(ubf(rv0.z << 16),         ca1.x, cb1.x), 0.f),
                             fmaxf(fmaf(ubf(rv0.z & 0xffff0000u), ca1.y, cb1.y), 0.f));
                a0.u.w = pk2(fmaxf(fmaf(ubf(rv0.w << 16),         ca1.z, cb1.z), 0.f),
                             fmaxf(fmaf(ubf(rv0.w & 0xffff0000u), ca1.w, cb1.w), 0.f));
                a1.u.x = pk2(fmaxf(fmaf(ubf(rv1.x << 16),         ca0.x, cb0.x), 0.f),
                             fmaxf(fmaf(ubf(rv1.x & 0xffff0000u), ca0.y, cb0.y), 0.f));
                a1.u.y = pk2(fmaxf(fmaf(ubf(rv1.y << 16),         ca0.z, cb0.z), 0.f),
                             fmaxf(fmaf(ubf(rv1.y & 0xffff0000u), ca0.w, cb0.w), 0.f));
                a1.u.z = pk2(fmaxf(fmaf(ubf(rv1.z << 16),         ca1.x, cb1.x), 0.f),
                             fmaxf(fmaf(ubf(rv1.z & 0xffff0000u), ca1.y, cb1.y), 0.f));
                a1.u.w = pk2(fmaxf(fmaf(ubf(rv1.w << 16),         ca1.z, cb1.z), 0.f),
                             fmaxf(fmaf(ubf(rv1.w & 0xffff0000u), ca1.w, cb1.w), 0.f));
                #pragma unroll
                for (int g = 0; g < 8; g++) {
                    short8 b = *(const short8*)(Bp + g * 16 * LDW + kk * 32);
                    acc[0][g] = __builtin_amdgcn_mfma_f32_16x16x32_bf16(a0.s, b, acc[0][g], 0, 0, 0);
                    acc[1][g] = __builtin_amdgcn_mfma_f32_16x16x32_bf16(a1.s, b, acc[1][g], 0, 0, 0);
                }
            }
        } else {
            const ushort* xp0 = xb + (size_t)(n0 + w * 32 + m) * F + koff;
            const ushort* xp1 = xp0 + 16 * F;
            #pragma unroll
            for (int kk = 0; kk < 4; kk++) {
                short8 a0 = *(const short8*)(xp0 + kk * 32);
                short8 a1 = *(const short8*)(xp1 + kk * 32);
                #pragma unroll
                for (int g = 0; g < 8; g++) {
                    short8 b = *(const short8*)(Bp + g * 16 * LDW + kk * 32);
                    acc[0][g] = __builtin_amdgcn_mfma_f32_16x16x32_bf16(a0, b, acc[0][g], 0, 0, 0);
                    acc[1][g] = __builtin_amdgcn_mfma_f32_16x16x32_bf16(a1, b, acc[1][g], 0, 0, 0);
                }
            }
        }
    }

    // epilogue: two-pass LDS transpose (64 rows x CTS f32 = 33.8 KB in Wt region),
    // then coalesced float4 row stores — avoids partial-line HBM write amplification.
    float* Ct = (float*)Wt;
    #pragma unroll
    for (int half = 0; half < 2; half++) {
        __syncthreads();   // Wt readers done (half 0) / prior stores done (half 1)
        if ((w >> 1) == half) {
            const int wl = w & 1;
            #pragma unroll
            for (int rg = 0; rg < 2; rg++) {
                const int rb = wl * 32 + rg * 16;
                #pragma unroll
                for (int g = 0; g < 8; g++) {
                    int c = g * 16 + m;
                    float bv = btot[c];
                    #pragma unroll
                    for (int i = 0; i < 4; i++) {
                        int lrow = rb + quad * 4 + i;
                        Ct[lrow * CTS + c] = acc[rg][g][i] + bv;
                    }
                }
            }
        }
        __syncthreads();
        #pragma unroll
        for (int p = 0; p < 8; p++) {
            int i4 = tid + p * 256;          // 2048 float4: 64 rows x 32
            int row = i4 >> 5;
            int c4 = (i4 & 31) * 4;
            int n = n0 + half * 64 + row;
            if (n < NN)
                *(float4*)(out + (size_t)n * F + c4) = *(const float4*)&Ct[row * CTS + c4];
        }
    }
}

extern "C" void kernel_launch(void* const* d_in, const int* in_sizes, int n_in,
                              void* d_out, int out_size, void* d_ws, size_t ws_size,
                              hipStream_t stream) {
    const float* x     = (const float*)d_in[0];
    const int*   ei    = (const int*)d_in[1];
    const int*   et    = (const int*)d_in[2];
    const float* Wself = (const float*)d_in[3];
    const float* bself = (const float*)d_in[4];
    const float* W1    = (const float*)d_in[5];
    const float* b1    = (const float*)d_in[6];
    const float* gamma = (const float*)d_in[7];
    const float* beta  = (const float*)d_in[8];
    const float* W2    = (const float*)d_in[9];
    const float* b2    = (const float*)d_in[10];
    float* out = (float*)d_out;

    // workspace layout
    ushort* hbuf = (ushort*)d_ws;                       // [4, NN, 128] bf16: h_in -> h1 in-place
    ushort* xb   = hbuf + (size_t)RN * F;               // [NN, 128] bf16
    ushort* Wt_g = xb + (size_t)NN * F;                 // [9, 128, 128] bf16
    float*  partials = (float*)(Wt_g + 9 * F * F);      // [4, NT1, 256]
    float*  sa    = partials + (size_t)NREL * NT1 * 256;// [4, 128]
    float*  sb    = sa + NREL * F;                      // [4, 128]
    float*  btot  = sb + NREL * F;                      // [128]
    int* counts     = (int*)(btot + F);                 // [RN]
    int* rowptr     = counts + RN;                      // [RN+1]
    int* cursor     = rowptr + RN + 1;                  // [RN]
    int* sorted_src = cursor + RN;                      // [NE]
    int* bsum       = sorted_src + NE;                  // [256]
    int* boff       = bsum + 256;                       // [256]

    hipMemsetAsync(counts, 0, (size_t)RN * sizeof(int), stream);

    prep_kernel<<<9, 256, 0, stream>>>(W1, W2, Wself, Wt_g);
    xb_kernel<<<NN * F / 1024, 256, 0, stream>>>(x, xb);
    hist_kernel<<<(NE + 255) / 256, 256, 0, stream>>>(ei, et, counts);
    scan1_kernel<<<NB, 256, 0, stream>>>(counts, rowptr, bsum);
    scan2_kernel<<<1, 256, 0, stream>>>(bsum, boff, rowptr);
    scan3_kernel<<<NB, 256, 0, stream>>>(rowptr, boff, cursor);
    reorder_kernel<<<(NE + 255) / 256, 256, 0, stream>>>(ei, et, cursor, sorted_src);
    gather_kernel<<<RN * 16 / 256, 256, 0, stream>>>(xb, rowptr, sorted_src, hbuf);
    {
        dim3 grid(NT1, NREL);
        gemm1_kernel<<<grid, 256, 0, stream>>>(hbuf, Wt_g, b1, partials);
    }
    bncoef_kernel<<<64, 256, 0, stream>>>(partials, gamma, beta, b2, bself, sa, sb, btot);
    gemm2_kernel<<<NT1, 256, 0, stream>>>(xb, hbuf, Wt_g, sa, sb, btot, out);
}

// Round 10
// 288.272 us; speedup vs baseline: 1.2256x; 1.1963x over previous
//
#include <hip/hip_runtime.h>

#define NN 50000
#define NE 800000
#define F 128
#define NREL 4
#define RN (NREL * NN)          // number of segments
#define NB 196                  // scan blocks: ceil(RN / 1024)
#define BN_EPS 1e-5f
#define TILE 128                // rows per block tile
#define NT1 391                 // ceil(NN / TILE)
#define LDW 136                 // padded LDS row stride in bf16 elems
#define CTS 132                 // padded f32 Ct row stride
#define XBB 6250                // xb blocks: NN*F/1024
#define HISTB 3125              // hist blocks: ceil(NE/256)

typedef __attribute__((ext_vector_type(8))) short short8;
typedef __attribute__((ext_vector_type(4))) float floatx4;

__device__ __forceinline__ ushort f2bf(float f) {
    union { float f; unsigned u; } v; v.f = f;
    unsigned r = v.u + 0x7fffu + ((v.u >> 16) & 1u);
    return (ushort)(r >> 16);
}
__device__ __forceinline__ float ubf(unsigned bits) {
    union { unsigned u; float f; } v; v.u = bits; return v.f;
}
__device__ __forceinline__ unsigned pk2(float a, float b) {
    return (unsigned)f2bf(a) | ((unsigned)f2bf(b) << 16);
}
__device__ __forceinline__ void acc_u4(float* acc, uint4 v) {
    acc[0] += ubf(v.x << 16); acc[1] += ubf(v.x & 0xffff0000u);
    acc[2] += ubf(v.y << 16); acc[3] += ubf(v.y & 0xffff0000u);
    acc[4] += ubf(v.z << 16); acc[5] += ubf(v.z & 0xffff0000u);
    acc[6] += ubf(v.w << 16); acc[7] += ubf(v.w & 0xffff0000u);
}

// ---- fused prep: [0,XBB) xb=bf16(x) | [XBB,XBB+9) weight transpose | rest: histogram ----
__global__ __launch_bounds__(256) void prep_all_kernel(
    const float* __restrict__ x, ushort* __restrict__ xb,
    const float* __restrict__ W1, const float* __restrict__ W2,
    const float* __restrict__ Wself, ushort* __restrict__ Wt_g,
    const int* __restrict__ ei, const int* __restrict__ et, int* __restrict__ counts)
{
    __shared__ ushort Lt[F * F];
    const int tid = threadIdx.x;
    const int b = blockIdx.x;
    if (b < XBB) {
        int i = b * 256 + tid;
        float4 v = *(const float4*)(x + (size_t)i * 4);
        uint2 u;
        u.x = pk2(v.x, v.y);
        u.y = pk2(v.z, v.w);
        *(uint2*)(xb + (size_t)i * 4) = u;
    } else if (b < XBB + 9) {
        int m = b - XBB;
        const float* src = (m < 4) ? (W1 + (size_t)m * F * F)
                         : (m < 8) ? (W2 + (size_t)(m - 4) * F * F)
                                   : Wself;
        #pragma unroll
        for (int p = 0; p < 16; p++) {
            int i4 = tid + p * 256;
            int k = i4 >> 5;
            int n4 = (i4 & 31) * 4;
            float4 v = *(const float4*)(src + (size_t)k * F + n4);
            Lt[(n4 + 0) * F + k] = f2bf(v.x);
            Lt[(n4 + 1) * F + k] = f2bf(v.y);
            Lt[(n4 + 2) * F + k] = f2bf(v.z);
            Lt[(n4 + 3) * F + k] = f2bf(v.w);
        }
        __syncthreads();
        #pragma unroll
        for (int p = 0; p < 8; p++) {
            int c = tid + p * 256;
            *(uint4*)(Wt_g + (size_t)m * F * F + c * 8) = *(const uint4*)&Lt[c * 8];
        }
    } else {
        int e = (b - XBB - 9) * 256 + tid;
        if (e < NE) atomicAdd(&counts[et[e] * NN + ei[NE + e]], 1);
    }
}

// ---------------- scan stage 1: per-block (1024) local exclusive scan ----------------
__global__ __launch_bounds__(256) void scan1_kernel(
    const int* __restrict__ counts, int* __restrict__ rowptr, int* __restrict__ bsum)
{
    __shared__ int wsum[4];
    const int tid = threadIdx.x;
    const int base = blockIdx.x * 1024 + tid * 4;
    int c[4];
    #pragma unroll
    for (int j = 0; j < 4; j++) c[j] = (base + j < RN) ? counts[base + j] : 0;
    int tsum = c[0] + c[1] + c[2] + c[3];
    const int lane = tid & 63, wv = tid >> 6;
    int s = tsum;
    #pragma unroll
    for (int d = 1; d < 64; d <<= 1) { int t = __shfl_up(s, d); if (lane >= d) s += t; }
    if (lane == 63) wsum[wv] = s;
    __syncthreads();
    int wave_off = 0;
    #pragma unroll
    for (int w = 0; w < 4; w++) if (w < wv) wave_off += wsum[w];
    int run = wave_off + s - tsum;
    #pragma unroll
    for (int j = 0; j < 4; j++) {
        if (base + j < RN) rowptr[base + j] = run;
        run += c[j];
    }
    if (tid == 0) bsum[blockIdx.x] = wsum[0] + wsum[1] + wsum[2] + wsum[3];
}

// ------- scan stage 2+3 merged: each block rescans bsum, adds its offset, inits cursor -------
__global__ __launch_bounds__(256) void scan3_kernel(
    int* __restrict__ rowptr, const int* __restrict__ bsum, int* __restrict__ cursor)
{
    __shared__ int wsum[4];
    __shared__ int sx[256];
    const int tid = threadIdx.x;
    int v = (tid < NB) ? bsum[tid] : 0;
    const int lane = tid & 63, wv = tid >> 6;
    int s = v;
    #pragma unroll
    for (int d = 1; d < 64; d <<= 1) { int t = __shfl_up(s, d); if (lane >= d) s += t; }
    if (lane == 63) wsum[wv] = s;
    __syncthreads();
    int wave_off = 0;
    #pragma unroll
    for (int w = 0; w < 4; w++) if (w < wv) wave_off += wsum[w];
    sx[tid] = wave_off + s - v;   // exclusive prefix at index tid
    __syncthreads();
    const int off = sx[blockIdx.x];
    if (blockIdx.x == 0 && tid == 0)
        rowptr[RN] = wsum[0] + wsum[1] + wsum[2] + wsum[3];   // == NE
    const int base = blockIdx.x * 1024 + tid * 4;
    #pragma unroll
    for (int j = 0; j < 4; j++) {
        int idx = base + j;
        if (idx < RN) { int t = rowptr[idx] + off; rowptr[idx] = t; cursor[idx] = t; }
    }
}

// ---------------- reorder ----------------
__global__ __launch_bounds__(256) void reorder_kernel(
    const int* __restrict__ ei, const int* __restrict__ et,
    int* __restrict__ cursor, int* __restrict__ sorted_src)
{
    int e = blockIdx.x * 256 + threadIdx.x;
    if (e >= NE) return;
    int key = et[e] * NN + ei[NE + e];
    int pos = atomicAdd(&cursor[key], 1);
    sorted_src[pos] = ei[e];
}

// ------- gather: hbuf[row] = bf16(xb[n] + sum_{e in seg(row)} xb[src_e]) -------
__global__ __launch_bounds__(256) void gather_kernel(
    const ushort* __restrict__ xb, const int* __restrict__ rowptr,
    const int* __restrict__ sorted_src, ushort* __restrict__ hbuf)
{
    const int t = blockIdx.x * 256 + threadIdx.x;
    const int row = t >> 4;               // segment id in [0, RN)
    const int lane = t & 15;              // 16 lanes x 8 bf16 = 128 feats
    const int n = row % NN;               // dst node

    const uint4* xv = (const uint4*)xb;   // row stride = 16 uint4
    float acc[8];
    {
        uint4 v = xv[n * 16 + lane];
        acc[0] = ubf(v.x << 16); acc[1] = ubf(v.x & 0xffff0000u);
        acc[2] = ubf(v.y << 16); acc[3] = ubf(v.y & 0xffff0000u);
        acc[4] = ubf(v.z << 16); acc[5] = ubf(v.z & 0xffff0000u);
        acc[6] = ubf(v.w << 16); acc[7] = ubf(v.w & 0xffff0000u);
    }
    int e = rowptr[row];
    const int e1 = rowptr[row + 1];
    for (; e + 4 <= e1; e += 4) {
        int s0 = sorted_src[e], s1 = sorted_src[e + 1];
        int s2 = sorted_src[e + 2], s3 = sorted_src[e + 3];
        uint4 a = xv[s0 * 16 + lane];
        uint4 b = xv[s1 * 16 + lane];
        uint4 c = xv[s2 * 16 + lane];
        uint4 d = xv[s3 * 16 + lane];
        acc_u4(acc, a); acc_u4(acc, b); acc_u4(acc, c); acc_u4(acc, d);
    }
    for (; e < e1; ++e) {
        int s0 = sorted_src[e];
        acc_u4(acc, xv[s0 * 16 + lane]);
    }
    uint4 o;
    o.x = pk2(acc[0], acc[1]);
    o.y = pk2(acc[2], acc[3]);
    o.z = pk2(acc[4], acc[5]);
    o.w = pk2(acc[6], acc[7]);
    *(uint4*)(hbuf + (size_t)row * F + lane * 8) = o;
}

// ------ GEMM1: h1 = bf16(hbuf @ W1[r] + b1[r]) in-place; per-block BN partials ------
__global__ __launch_bounds__(256, 4) void gemm1_kernel(
    ushort* __restrict__ hbuf, const ushort* __restrict__ Wt_g,
    const float* __restrict__ b1, float* __restrict__ partials)
{
    __shared__ __attribute__((aligned(16))) ushort Wt[F * LDW];   // 34.8 KB, reused as At
    __shared__ float csum[F], csq[F];

    const int tid = threadIdx.x;
    const int r = blockIdx.y;
    const int n0 = blockIdx.x * TILE;
    const int lane = tid & 63, w = tid >> 6;
    const int m = lane & 15, quad = lane >> 4;

    if (tid < F) { csum[tid] = 0.f; csq[tid] = 0.f; }

    // stage Wt (128 rows x 16 chunks of 8 ushorts)
    {
        const ushort* wg = Wt_g + (size_t)r * F * F;
        #pragma unroll
        for (int p = 0; p < 8; p++) {
            int c = tid + p * 256;
            int n = c >> 4, off = (c & 15) * 8;
            *(uint4*)&Wt[n * LDW + off] = *(const uint4*)(wg + c * 8);
        }
    }
    __syncthreads();

    // A direct from global: rows w*32 + {0..15, 16..31}
    const ushort* Ap0 = hbuf + ((size_t)r * NN + n0 + w * 32 + m) * F + quad * 8;
    const ushort* Ap1 = Ap0 + 16 * F;
    const ushort* Bp  = &Wt[m * LDW + quad * 8];

    floatx4 acc[2][8];
    #pragma unroll
    for (int rg = 0; rg < 2; rg++)
        #pragma unroll
        for (int g = 0; g < 8; g++) acc[rg][g] = (floatx4)0.f;

    #pragma unroll
    for (int kk = 0; kk < 4; kk++) {
        short8 a0 = *(const short8*)(Ap0 + kk * 32);
        short8 a1 = *(const short8*)(Ap1 + kk * 32);
        #pragma unroll
        for (int g = 0; g < 8; g++) {
            short8 b = *(const short8*)(Bp + g * 16 * LDW + kk * 32);
            acc[0][g] = __builtin_amdgcn_mfma_f32_16x16x32_bf16(a0, b, acc[0][g], 0, 0, 0);
            acc[1][g] = __builtin_amdgcn_mfma_f32_16x16x32_bf16(a1, b, acc[1][g], 0, 0, 0);
        }
    }
    __syncthreads();   // all waves done reading Wt -> reuse as At

    ushort* At = Wt;
    #pragma unroll
    for (int rg = 0; rg < 2; rg++) {
        const int rb = w * 32 + rg * 16;
        #pragma unroll
        for (int g = 0; g < 8; g++) {
            int c = g * 16 + m;
            float bv = b1[r * F + c];
            float ls = 0.f, lq = 0.f;
            #pragma unroll
            for (int i = 0; i < 4; i++) {
                int lrow = rb + quad * 4 + i;
                float v = acc[rg][g][i] + bv;
                At[lrow * LDW + c] = f2bf(v);
                if (n0 + lrow < NN) { ls += v; lq += v * v; }
            }
            ls += __shfl_xor(ls, 16); ls += __shfl_xor(ls, 32);
            lq += __shfl_xor(lq, 16); lq += __shfl_xor(lq, 32);
            if (quad == 0) { atomicAdd(&csum[c], ls); atomicAdd(&csq[c], lq); }
        }
    }
    __syncthreads();

    // coalesced in-place write-back + one coalesced partial row per block
    #pragma unroll
    for (int p = 0; p < 8; p++) {
        int cc = tid + p * 256;
        int row = cc >> 4, off = (cc & 15) * 8;
        if (n0 + row < NN)
            *(uint4*)(hbuf + ((size_t)r * NN + n0 + row) * F + off) =
                *(const uint4*)&At[row * LDW + off];
    }
    partials[((size_t)r * NT1 + blockIdx.x) * 256 + tid] =
        (tid < F) ? csum[tid] : csq[tid - F];
}

// ---------------- bncoef: parallel reduce partials -> sa/sb; btot ----------------
__global__ __launch_bounds__(256) void bncoef_kernel(
    const float* __restrict__ partials,
    const float* __restrict__ gamma, const float* __restrict__ beta,
    const float* __restrict__ b2, const float* __restrict__ bself,
    float* __restrict__ sa, float* __restrict__ sb, float* __restrict__ btot)
{
    const int tid = threadIdx.x;
    const int pair = blockIdx.x * 8 + (tid >> 5);     // 0..511
    const int l32 = tid & 31;
    const int rel = pair >> 7;
    const int col = pair & 127;
    const float* p = partials + (size_t)rel * NT1 * 256;
    float s = 0.f, q = 0.f;
    for (int b = l32; b < NT1; b += 32) {
        s += p[b * 256 + col];
        q += p[b * 256 + 128 + col];
    }
    #pragma unroll
    for (int d = 1; d < 32; d <<= 1) {
        s += __shfl_xor(s, d, 32);
        q += __shfl_xor(q, d, 32);
    }
    if (l32 == 0) {
        float mean = s * (1.0f / NN);
        float var = q * (1.0f / NN) - mean * mean;
        float g = gamma[pair] * rsqrtf(var + BN_EPS);
        sa[pair] = g;
        sb[pair] = beta[pair] - mean * g;
    }
    if (blockIdx.x == 0 && tid < F)
        btot[tid] = bself[tid] + b2[tid] + b2[F + tid] + b2[2 * F + tid] + b2[3 * F + tid];
}

// ------- GEMM2 (512 threads, 8 waves x 16 rows): out = xb@Wself + sum_r relu(bn(h1_r))@W2[r] + btot -------
__global__ __launch_bounds__(512, 2) void gemm2_kernel(
    const ushort* __restrict__ xb, const ushort* __restrict__ h1,
    const ushort* __restrict__ Wt_g,
    const float* __restrict__ sa, const float* __restrict__ sb,
    const float* __restrict__ btot, float* __restrict__ out)
{
    __shared__ __attribute__((aligned(16))) ushort Wt[F * LDW];   // 34.8 KB; Ct reuse
    __shared__ float sAl[NREL * F], sBl[NREL * F];

    const int tid = threadIdx.x;
    const int n0 = blockIdx.x * TILE;
    const int lane = tid & 63, w = tid >> 6;      // w = 0..7
    const int m = lane & 15, quad = lane >> 4;
    const int koff = quad * 8;

    sAl[tid] = sa[tid];
    sBl[tid] = sb[tid];

    floatx4 acc[8];
    #pragma unroll
    for (int g = 0; g < 8; g++) acc[g] = (floatx4)0.f;

    for (int rel = 0; rel < 5; rel++) {
        __syncthreads();   // prior Wt readers done (and sAl/sBl ready on first iter)
        {
            int mat = (rel < 4) ? (NREL + rel) : 8;
            const ushort* wg = Wt_g + (size_t)mat * F * F;
            #pragma unroll
            for (int p = 0; p < 4; p++) {
                int c = tid + p * 512;
                int n = c >> 4, off = (c & 15) * 8;
                *(uint4*)&Wt[n * LDW + off] = *(const uint4*)(wg + c * 8);
            }
        }
        __syncthreads();
        const ushort* Bp = &Wt[m * LDW + koff];
        if (rel < 4) {
            const ushort* hp = h1 + ((size_t)rel * NN + n0 + w * 16 + m) * F + koff;
            #pragma unroll
            for (int kk = 0; kk < 4; kk++) {
                uint4 rv = *(const uint4*)(hp + kk * 32);
                float4 ca0 = *(const float4*)(&sAl[rel * F + koff + kk * 32]);
                float4 ca1 = *(const float4*)(&sAl[rel * F + koff + kk * 32 + 4]);
                float4 cb0 = *(const float4*)(&sBl[rel * F + koff + kk * 32]);
                float4 cb1 = *(const float4*)(&sBl[rel * F + koff + kk * 32 + 4]);
                union { uint4 u; short8 s; } a0;
                a0.u.x = pk2(fmaxf(fmaf(ubf(rv.x << 16),         ca0.x, cb0.x), 0.f),
                             fmaxf(fmaf(ubf(rv.x & 0xffff0000u), ca0.y, cb0.y), 0.f));
                a0.u.y = pk2(fmaxf(fmaf(ubf(rv.y << 16),         ca0.z, cb0.z), 0.f),
                             fmaxf(fmaf(ubf(rv.y & 0xffff0000u), ca0.w, cb0.w), 0.f));
                a0.u.z = pk2(fmaxf(fmaf(ubf(rv.z << 16),         ca1.x, cb1.x), 0.f),
                             fmaxf(fmaf(ubf(rv.z & 0xffff0000u), ca1.y, cb1.y), 0.f));
                a0.u.w = pk2(fmaxf(fmaf(ubf(rv.w << 16),         ca1.z, cb1.z), 0.f),
                             fmaxf(fmaf(ubf(rv.w & 0xffff0000u), ca1.w, cb1.w), 0.f));
                #pragma unroll
                for (int g = 0; g < 8; g++) {
                    short8 b = *(const short8*)(Bp + g * 16 * LDW + kk * 32);
                    acc[g] = __builtin_amdgcn_mfma_f32_16x16x32_bf16(a0.s, b, acc[g], 0, 0, 0);
                }
            }
        } else {
            const ushort* xp = xb + (size_t)(n0 + w * 16 + m) * F + koff;
            #pragma unroll
            for (int kk = 0; kk < 4; kk++) {
                short8 a0 = *(const short8*)(xp + kk * 32);
                #pragma unroll
                for (int g = 0; g < 8; g++) {
                    short8 b = *(const short8*)(Bp + g * 16 * LDW + kk * 32);
                    acc[g] = __builtin_amdgcn_mfma_f32_16x16x32_bf16(a0, b, acc[g], 0, 0, 0);
                }
            }
        }
    }

    // epilogue: two-pass LDS transpose (64 rows x CTS f32 = 33.8 KB in Wt region),
    // then coalesced float4 row stores.
    float* Ct = (float*)Wt;
    #pragma unroll
    for (int half = 0; half < 2; half++) {
        __syncthreads();   // Wt readers done (half 0) / prior stores done (half 1)
        if ((w >> 2) == half) {
            const int rb = (w & 3) * 16;
            #pragma unroll
            for (int g = 0; g < 8; g++) {
                int c = g * 16 + m;
                float bv = btot[c];
                #pragma unroll
                for (int i = 0; i < 4; i++) {
                    int lrow = rb + quad * 4 + i;
                    Ct[lrow * CTS + c] = acc[g][i] + bv;
                }
            }
        }
        __syncthreads();
        #pragma unroll
        for (int p = 0; p < 4; p++) {
            int i4 = tid + p * 512;          // 2048 float4: 64 rows x 32
            int row = i4 >> 5;
            int c4 = (i4 & 31) * 4;
            int n = n0 + half * 64 + row;
            if (n < NN)
                *(float4*)(out + (size_t)n * F + c4) = *(const float4*)&Ct[row * CTS + c4];
        }
    }
}

extern "C" void kernel_launch(void* const* d_in, const int* in_sizes, int n_in,
                              void* d_out, int out_size, void* d_ws, size_t ws_size,
                              hipStream_t stream) {
    const float* x     = (const float*)d_in[0];
    const int*   ei    = (const int*)d_in[1];
    const int*   et    = (const int*)d_in[2];
    const float* Wself = (const float*)d_in[3];
    const float* bself = (const float*)d_in[4];
    const float* W1    = (const float*)d_in[5];
    const float* b1    = (const float*)d_in[6];
    const float* gamma = (const float*)d_in[7];
    const float* beta  = (const float*)d_in[8];
    const float* W2    = (const float*)d_in[9];
    const float* b2    = (const float*)d_in[10];
    float* out = (float*)d_out;

    // workspace layout
    ushort* hbuf = (ushort*)d_ws;                       // [4, NN, 128] bf16: h_in -> h1 in-place
    ushort* xb   = hbuf + (size_t)RN * F;               // [NN, 128] bf16
    ushort* Wt_g = xb + (size_t)NN * F;                 // [9, 128, 128] bf16
    float*  partials = (float*)(Wt_g + 9 * F * F);      // [4, NT1, 256]
    float*  sa    = partials + (size_t)NREL * NT1 * 256;// [4, 128]
    float*  sb    = sa + NREL * F;                      // [4, 128]
    float*  btot  = sb + NREL * F;                      // [128]
    int* counts     = (int*)(btot + F);                 // [RN]
    int* rowptr     = counts + RN;                      // [RN+1]
    int* cursor     = rowptr + RN + 1;                  // [RN]
    int* sorted_src = cursor + RN;                      // [NE]
    int* bsum       = sorted_src + NE;                  // [256]

    hipMemsetAsync(counts, 0, (size_t)RN * sizeof(int), stream);

    prep_all_kernel<<<XBB + 9 + HISTB, 256, 0, stream>>>(
        x, xb, W1, W2, Wself, Wt_g, ei, et, counts);
    scan1_kernel<<<NB, 256, 0, stream>>>(counts, rowptr, bsum);
    scan3_kernel<<<NB, 256, 0, stream>>>(rowptr, bsum, cursor);
    reorder_kernel<<<(NE + 255) / 256, 256, 0, stream>>>(ei, et, cursor, sorted_src);
    gather_kernel<<<RN * 16 / 256, 256, 0, stream>>>(xb, rowptr, sorted_src, hbuf);
    {
        dim3 grid(NT1, NREL);
        gemm1_kernel<<<grid, 256, 0, stream>>>(hbuf, Wt_g, b1, partials);
    }
    bncoef_kernel<<<64, 256, 0, stream>>>(partials, gamma, beta, b2, bself, sa, sb, btot);
    gemm2_kernel<<<NT1, 512, 0, stream>>>(xb, hbuf, Wt_g, sa, sb, btot, out);
}